// Round 10
// baseline (42.907 us; speedup 1.0000x reference)
//
#include <hip/hip_runtime.h>

typedef __fp16   pk16x2 __attribute__((ext_vector_type(2)));
typedef _Float16 f16x8  __attribute__((ext_vector_type(8)));
typedef float    f32x4  __attribute__((ext_vector_type(4)));
typedef float    f32x16 __attribute__((ext_vector_type(16)));

#define BATCH 65536
#define NIN   128
#define NOUT  128

#define L2E   1.4426950408889634f
#define SQL2E 1.2011224087864498f     /* sqrt(log2 e) */
#define EM2   0.1353352832366127f     /* e^-2 */

// ---------------------------------------------------------------------------
// MFMA 32x32x16 f16. A-frag: lane -> row = l&31, k = (l>>5)*8 + e.
// B-frag: lane -> col = l&31, k = (l>>5)*8 + e. C/D: col = l&31,
// row = (reg&3) + 8*(reg>>2) + 4*(l>>5).
//
// K-order (72 ksteps of 16): basis ks = g*8 + t2 (g=0..7):
//   k-slot sub*8+e -> j = g*16 + sub*8 + t2, grid = e
//   (lane consumes 8 CONSECUTIVE x floats per group). silu ks = 64+s:
//   j = s*16 + sub*8 + e.
//
// W5 (kan_prep): 2 col-halves x 72 ksteps x 2 KB. Within half h, kstep ks,
// chunk c2 = nbb2*64 + lane2 (16 B): col = h*64 + nbb2*32 + (lane2&31),
// sub = lane2>>5:
//   ks < 64 : coeffs[col][(ks>>3)*16 + sub*8 + (ks&7)][e]
//   ks >= 64: base_w[col][(ks-64)*16 + sub*8 + e]
// Fragment ds_read: 64 lanes x 16 B consecutive -> conflict-free.
// Groups of 8 ksteps (16 KB) staged linearly via global_load_lds, dbuffered.
// ---------------------------------------------------------------------------

__global__ __launch_bounds__(256) void kan_prep(const float* __restrict__ coeffs,
                                                const float* __restrict__ base_w,
                                                _Float16* __restrict__ W5) {
    int t = blockIdx.x * 256 + threadIdx.x;   // chunk id, 0..18431
    int h     = t / 9216;
    int rem   = t - h * 9216;
    int ks    = rem >> 7;
    int c2    = rem & 127;
    int nbb2  = c2 >> 6;
    int lane2 = c2 & 63;
    int sub   = lane2 >> 5;
    int col   = h * 64 + nbb2 * 32 + (lane2 & 31);
    const float* src;
    if (ks < 64) {
        int g = ks >> 3, t2 = ks & 7;
        src = coeffs + ((size_t)col * 128 + g * 16 + sub * 8 + t2) * 8;
    } else {
        src = base_w + (size_t)col * 128 + (ks - 64) * 16 + sub * 8;
    }
    f16x8 v;
#pragma unroll
    for (int e = 0; e < 8; ++e) v[e] = (_Float16)src[e];
    *(f16x8*)((char*)W5 + (size_t)t * 16) = v;
}

__device__ __forceinline__ void gll16(const void* g, void* l) {
    __builtin_amdgcn_global_load_lds(
        (const __attribute__((address_space(1))) unsigned int*)g,
        (__attribute__((address_space(3))) unsigned int*)l, 16, 0, 0);
}

// b_g = exp(-(t-g)^2), t = 3.5*(x+1): 2 exp + mul chain, pkrtz packing.
__device__ __forceinline__ f16x8 basis8r(float t) {
    float u  = t * SQL2E;
    float b0 = __builtin_amdgcn_exp2f(-(u * u));                              // e^{-t^2}
    float r  = __builtin_amdgcn_exp2f(__builtin_fmaf(t, 2.0f * L2E, -L2E));   // e^{2t-1}
    float b1 = b0 * r; r *= EM2;
    float b2 = b1 * r; r *= EM2;
    float b3 = b2 * r; r *= EM2;
    float b4 = b3 * r; r *= EM2;
    float b5 = b4 * r; r *= EM2;
    float b6 = b5 * r; r *= EM2;
    float b7 = b6 * r;
    pk16x2 p0 = __builtin_amdgcn_cvt_pkrtz(b0, b1);
    pk16x2 p1 = __builtin_amdgcn_cvt_pkrtz(b2, b3);
    pk16x2 p2 = __builtin_amdgcn_cvt_pkrtz(b4, b5);
    pk16x2 p3 = __builtin_amdgcn_cvt_pkrtz(b6, b7);
    f16x8 o;
    o[0] = p0[0]; o[1] = p0[1]; o[2] = p1[0]; o[3] = p1[1];
    o[4] = p2[0]; o[5] = p2[1]; o[6] = p3[0]; o[7] = p3[1];
    return o;
}

__device__ __forceinline__ float silu1(float xv) {
    float p = __builtin_amdgcn_exp2f(-xv * L2E);
    return xv * __builtin_amdgcn_rcpf(1.0f + p);
}

// 256 threads = 4 row-stacked waves; wave = 32 rows x 64 cols (m=1, nbb2=2,
// acc = 32 VGPR). Block = 128 rows x one 64-col half. Grid 1024 ->
// 4 blocks/CU (32 KB LDS each) -> 16 waves/CU = 4/SIMD, with 4 staggered
// barrier domains per CU. launch_bounds(256,4) caps VGPR at 128.
__global__ __launch_bounds__(256, 4) void kan_main(const float* __restrict__ x,
                                                   const _Float16* __restrict__ W5,
                                                   float* __restrict__ out) {
    __shared__ _Float16 smem[2][8192];   // 2 x 16 KB (8 ksteps x 2 KB)

    const int tid  = threadIdx.x;
    const int lane = tid & 63;
    const int w    = tid >> 6;
    const int l31  = lane & 31;
    const int sub  = lane >> 5;
    const int h    = blockIdx.x & 1;
    const int row0 = (blockIdx.x >> 1) * 128 + w * 32;
    const int col0 = h * 64;

    const float* xp = x + (size_t)(row0 + l31) * NIN;   // lane's x row

    f32x16 acc[2];
#pragma unroll
    for (int nbb = 0; nbb < 2; ++nbb)
#pragma unroll
        for (int r = 0; r < 16; ++r) acc[nbb][r] = 0.f;

    const char* wbase = (const char*)W5 + (size_t)h * 147456;
#define STAGE(buf, grp)                                                         \
    do {                                                                        \
        const char* _s = wbase + (size_t)(grp) * 16384 + (size_t)tid * 16;      \
        char*       _d = (char*)&smem[(buf)][0] + (size_t)tid * 16;             \
        _Pragma("unroll")                                                       \
        for (int _i = 0; _i < 4; ++_i) gll16(_s + _i * 4096, _d + _i * 4096);   \
    } while (0)

    STAGE(0, 0);
    // prefetch x for group 0
    f32x4 xa = *(const f32x4*)(xp + sub * 8);
    f32x4 xb = *(const f32x4*)(xp + sub * 8 + 4);
    __syncthreads();

    // ---- 8 basis groups of 8 ksteps (K = 1024) ----
#pragma unroll
    for (int g = 0; g < 8; ++g) {
        const int cur = g & 1;
        STAGE(cur ^ 1, g + 1);            // g == 7 stages the silu group
        // prefetch next group's x (g=7 -> silu s=0's x)
        const int nxt = (g < 7) ? (g + 1) * 16 : 0;
        f32x4 xa2 = *(const f32x4*)(xp + nxt + sub * 8);
        f32x4 xb2 = *(const f32x4*)(xp + nxt + sub * 8 + 4);

        // pregenerate the group's 8 A-fragments (8 independent chains)
        f16x8 a[8];
#pragma unroll
        for (int t2 = 0; t2 < 4; ++t2) a[t2]     = basis8r(__builtin_fmaf(xa[t2], 3.5f, 3.5f));
#pragma unroll
        for (int t2 = 0; t2 < 4; ++t2) a[4 + t2] = basis8r(__builtin_fmaf(xb[t2], 3.5f, 3.5f));

        // MFMA cluster: 8 ksteps x 2 nbb
#pragma unroll
        for (int t2 = 0; t2 < 8; ++t2) {
            const char* bp = (const char*)&smem[cur][0] + t2 * 2048 + lane * 16;
            f16x8 b0 = *(const f16x8*)bp;
            f16x8 b1 = *(const f16x8*)(bp + 1024);
            acc[0] = __builtin_amdgcn_mfma_f32_32x32x16_f16(a[t2], b0, acc[0], 0, 0, 0);
            acc[1] = __builtin_amdgcn_mfma_f32_32x32x16_f16(a[t2], b1, acc[1], 0, 0, 0);
        }
        xa = xa2; xb = xb2;
        __syncthreads();
    }

    // ---- silu group: 8 ksteps (K = 128); buffer 0 holds ksteps 64..71 ----
#pragma unroll
    for (int s = 0; s < 8; ++s) {
        f32x4 xa2, xb2;
        if (s < 7) {
            xa2 = *(const f32x4*)(xp + (s + 1) * 16 + sub * 8);
            xb2 = *(const f32x4*)(xp + (s + 1) * 16 + sub * 8 + 4);
        }
        float s0 = silu1(xa[0]), s1 = silu1(xa[1]), s2 = silu1(xa[2]), s3 = silu1(xa[3]);
        float s4 = silu1(xb[0]), s5 = silu1(xb[1]), s6 = silu1(xb[2]), s7 = silu1(xb[3]);
        pk16x2 p0 = __builtin_amdgcn_cvt_pkrtz(s0, s1);
        pk16x2 p1 = __builtin_amdgcn_cvt_pkrtz(s2, s3);
        pk16x2 p2 = __builtin_amdgcn_cvt_pkrtz(s4, s5);
        pk16x2 p3 = __builtin_amdgcn_cvt_pkrtz(s6, s7);
        f16x8 a;
        a[0] = p0[0]; a[1] = p0[1]; a[2] = p1[0]; a[3] = p1[1];
        a[4] = p2[0]; a[5] = p2[1]; a[6] = p3[0]; a[7] = p3[1];
        const char* bp = (const char*)&smem[0][0] + s * 2048 + lane * 16;
        f16x8 b0 = *(const f16x8*)bp;
        f16x8 b1 = *(const f16x8*)(bp + 1024);
        acc[0] = __builtin_amdgcn_mfma_f32_32x32x16_f16(a, b0, acc[0], 0, 0, 0);
        acc[1] = __builtin_amdgcn_mfma_f32_32x32x16_f16(a, b1, acc[1], 0, 0, 0);
        if (s < 7) { xa = xa2; xb = xb2; }
    }

    // ---- Epilogue: row = (r&3) + 8*(r>>2) + 4*sub, col = col0 + nbb*32 + l31
#pragma unroll
    for (int nbb = 0; nbb < 2; ++nbb)
#pragma unroll
        for (int r = 0; r < 16; ++r) {
            int crow = (r & 3) + 8 * (r >> 2) + 4 * sub;
            out[(size_t)(row0 + crow) * NOUT + col0 + nbb * 32 + l31] = acc[nbb][r];
        }
}

extern "C" void kernel_launch(void* const* d_in, const int* in_sizes, int n_in,
                              void* d_out, int out_size, void* d_ws, size_t ws_size,
                              hipStream_t stream) {
    const float* x       = (const float*)d_in[0];
    const float* coeffs  = (const float*)d_in[1];
    const float* base_w  = (const float*)d_in[2];
    _Float16* W5 = (_Float16*)d_ws;   // 2 halves x 144 KB = 294912 bytes

    kan_prep<<<dim3(72), dim3(256), 0, stream>>>(coeffs, base_w, W5);
    kan_main<<<dim3(BATCH / 64), dim3(256), 0, stream>>>(x, W5, (float*)d_out);
}

// Round 11
// 37.170 us; speedup vs baseline: 1.1543x; 1.1543x over previous
//
#include <hip/hip_runtime.h>

typedef __fp16   pk16x2 __attribute__((ext_vector_type(2)));
typedef _Float16 f16x8  __attribute__((ext_vector_type(8)));
typedef float    f32x4  __attribute__((ext_vector_type(4)));
typedef float    f32x16 __attribute__((ext_vector_type(16)));

#define BATCH 65536
#define NIN   128
#define NOUT  128

#define L2E   1.4426950408889634f
#define SQL2E 1.2011224087864498f     /* sqrt(log2 e) */
#define EM2   0.1353352832366127f     /* e^-2 */

// ---------------------------------------------------------------------------
// MFMA 32x32x16 f16. A-frag: lane -> row = l&31, k = (l>>5)*8 + e.
// B-frag: lane -> col = l&31, k = (l>>5)*8 + e. C/D: col = l&31,
// row = (reg&3) + 8*(reg>>2) + 4*(l>>5).
//
// K-order (72 ksteps of 16): basis ks = g*8 + t2 (g=0..7):
//   k-slot sub*8+e -> j = g*16 + sub*8 + t2, grid = e
//   (lane consumes 8 CONSECUTIVE x floats per group). silu ks = 64+s:
//   j = s*16 + sub*8 + e.
//
// W3 (kan_prep): 72 tiles x 4 KB; tile ks, chunk c = nbb*64 + lane (16 B):
//   col = nbb*32 + (lane&31), sub = lane>>5:
//     ks < 64 : coeffs[col][(ks>>3)*16 + sub*8 + (ks&7)][e]
//     ks >= 64: base_w[col][(ks-64)*16 + sub*8 + e]
// Fragment ds_read: 64 lanes x 16 B consecutive -> conflict-free (verified).
//
// PHASE ROTATION (new): block processes basis groups in order
// (start+i) & 7, start = blockIdx & 7. The 2 co-resident blocks on a CU are
// thereby at different pipeline phases -> wave-A's VALU burst overlaps
// wave-B's MFMA/LDS burst on every SIMD (each SIMD hosts 1 wave per block).
// K-sum order is commutative, so results are unchanged.
// ---------------------------------------------------------------------------

__global__ __launch_bounds__(256) void kan_prep(const float* __restrict__ coeffs,
                                                const float* __restrict__ base_w,
                                                _Float16* __restrict__ W3) {
    int t = blockIdx.x * 256 + threadIdx.x;   // chunk id, 0..18431
    int ks   = t >> 8;
    int c    = t & 255;
    int nbb  = c >> 6;
    int lane = c & 63;
    int sub  = lane >> 5;
    int col  = nbb * 32 + (lane & 31);
    f16x8 v;
    if (ks < 64) {
        int g = ks >> 3, t2 = ks & 7;
        const float* src = coeffs + ((size_t)col * 128 + g * 16 + sub * 8 + t2) * 8;
#pragma unroll
        for (int e = 0; e < 8; ++e) v[e] = (_Float16)src[e];
    } else {
        const float* src = base_w + (size_t)col * 128 + (ks - 64) * 16 + sub * 8;
#pragma unroll
        for (int e = 0; e < 8; ++e) v[e] = (_Float16)src[e];
    }
    *(f16x8*)((char*)W3 + (size_t)t * 16) = v;
}

__device__ __forceinline__ void gll16(const void* g, void* l) {
    __builtin_amdgcn_global_load_lds(
        (const __attribute__((address_space(1))) unsigned int*)g,
        (__attribute__((address_space(3))) unsigned int*)l, 16, 0, 0);
}

// b_g = exp(-(t-g)^2), t = 3.5*(x+1): 2 exp + mul chain, pkrtz packing.
__device__ __forceinline__ f16x8 basis8r(float t) {
    float u  = t * SQL2E;
    float b0 = __builtin_amdgcn_exp2f(-(u * u));                              // e^{-t^2}
    float r  = __builtin_amdgcn_exp2f(__builtin_fmaf(t, 2.0f * L2E, -L2E));   // e^{2t-1}
    float b1 = b0 * r; r *= EM2;
    float b2 = b1 * r; r *= EM2;
    float b3 = b2 * r; r *= EM2;
    float b4 = b3 * r; r *= EM2;
    float b5 = b4 * r; r *= EM2;
    float b6 = b5 * r; r *= EM2;
    float b7 = b6 * r;
    pk16x2 p0 = __builtin_amdgcn_cvt_pkrtz(b0, b1);
    pk16x2 p1 = __builtin_amdgcn_cvt_pkrtz(b2, b3);
    pk16x2 p2 = __builtin_amdgcn_cvt_pkrtz(b4, b5);
    pk16x2 p3 = __builtin_amdgcn_cvt_pkrtz(b6, b7);
    f16x8 o;
    o[0] = p0[0]; o[1] = p0[1]; o[2] = p1[0]; o[3] = p1[1];
    o[4] = p2[0]; o[5] = p2[1]; o[6] = p3[0]; o[7] = p3[1];
    return o;
}

__device__ __forceinline__ float silu1(float xv) {
    float p = __builtin_amdgcn_exp2f(-xv * L2E);
    return xv * __builtin_amdgcn_rcpf(1.0f + p);
}

// 256 threads = 4 row-stacked waves. Wave owns 32 rows x 128 cols (m=1,
// nbb=4): every basis value computed ONCE device-wide (d=1). Grid 512 ->
// 2 blocks/CU (64 KB LDS each) -> 8 waves/CU = 2/SIMD, one wave per block
// per SIMD; blocks rotated out of phase.
__global__ __launch_bounds__(256, 2) void kan_main(const float* __restrict__ x,
                                                   const _Float16* __restrict__ W3,
                                                   float* __restrict__ out) {
    __shared__ _Float16 smem[2][16384];   // 2 x 32 KB (8 k-step tiles each)

    const int tid   = threadIdx.x;
    const int lane  = tid & 63;
    const int w     = tid >> 6;
    const int l31   = lane & 31;
    const int sub   = lane >> 5;
    const int row0  = blockIdx.x * 128 + w * 32;
    const int start = blockIdx.x & 7;    // phase rotation

    const float* xp = x + (size_t)(row0 + l31) * NIN;   // lane's x row

    f32x16 acc[4];
#pragma unroll
    for (int nbb = 0; nbb < 4; ++nbb)
#pragma unroll
        for (int r = 0; r < 16; ++r) acc[nbb][r] = 0.f;

    const char* wbase = (const char*)W3;
#define STAGE(buf, grp)                                                         \
    do {                                                                        \
        const char* _s = wbase + (size_t)(grp) * 32768 + (size_t)tid * 16;      \
        char*       _d = (char*)&smem[(buf)][0] + (size_t)tid * 16;             \
        _Pragma("unroll")                                                       \
        for (int _i = 0; _i < 8; ++_i) gll16(_s + _i * 4096, _d + _i * 4096);   \
    } while (0)

    STAGE(0, start);
    // prefetch x for first group
    f32x4 xa = *(const f32x4*)(xp + start * 16 + sub * 8);
    f32x4 xb = *(const f32x4*)(xp + start * 16 + sub * 8 + 4);
    __syncthreads();

    // ---- 8 basis groups of 8 ksteps (K = 1024), rotated order ----
#pragma unroll
    for (int i = 0; i < 8; ++i) {
        const int cur = i & 1;
        // stage next: basis group (start+i+1)&7, or silu group (8) at i==7
        const int nxtg = (i < 7) ? ((start + i + 1) & 7) : 8;
        STAGE(cur ^ 1, nxtg);
        // prefetch next group's x (silu s=0 x when i==7)
        const int nxt = (i < 7) ? (((start + i + 1) & 7) * 16) : 0;
        f32x4 xa2 = *(const f32x4*)(xp + nxt + sub * 8);
        f32x4 xb2 = *(const f32x4*)(xp + nxt + sub * 8 + 4);

        // pregenerate the group's 8 A-fragments (8 independent chains)
        f16x8 a[8];
#pragma unroll
        for (int t2 = 0; t2 < 4; ++t2) a[t2]     = basis8r(__builtin_fmaf(xa[t2], 3.5f, 3.5f));
#pragma unroll
        for (int t2 = 0; t2 < 4; ++t2) a[4 + t2] = basis8r(__builtin_fmaf(xb[t2], 3.5f, 3.5f));

        // MFMA cluster: 8 ksteps x 4 nbb, priority-boosted
        __builtin_amdgcn_s_setprio(1);
#pragma unroll
        for (int t2 = 0; t2 < 8; ++t2) {
            const char* bp = (const char*)&smem[cur][0] + t2 * 4096 + lane * 16;
#pragma unroll
            for (int nbb = 0; nbb < 4; ++nbb) {
                f16x8 b = *(const f16x8*)(bp + nbb * 1024);
                acc[nbb] = __builtin_amdgcn_mfma_f32_32x32x16_f16(a[t2], b, acc[nbb], 0, 0, 0);
            }
        }
        __builtin_amdgcn_s_setprio(0);
        xa = xa2; xb = xb2;
        __syncthreads();
    }

    // ---- silu group: 8 ksteps (K = 128); buffer 0 holds tiles 64..71 ----
#pragma unroll
    for (int s = 0; s < 8; ++s) {
        f32x4 xa2, xb2;
        if (s < 7) {
            xa2 = *(const f32x4*)(xp + (s + 1) * 16 + sub * 8);
            xb2 = *(const f32x4*)(xp + (s + 1) * 16 + sub * 8 + 4);
        }
        float s0 = silu1(xa[0]), s1 = silu1(xa[1]), s2 = silu1(xa[2]), s3 = silu1(xa[3]);
        float s4 = silu1(xb[0]), s5 = silu1(xb[1]), s6 = silu1(xb[2]), s7 = silu1(xb[3]);
        pk16x2 p0 = __builtin_amdgcn_cvt_pkrtz(s0, s1);
        pk16x2 p1 = __builtin_amdgcn_cvt_pkrtz(s2, s3);
        pk16x2 p2 = __builtin_amdgcn_cvt_pkrtz(s4, s5);
        pk16x2 p3 = __builtin_amdgcn_cvt_pkrtz(s6, s7);
        f16x8 a;
        a[0] = p0[0]; a[1] = p0[1]; a[2] = p1[0]; a[3] = p1[1];
        a[4] = p2[0]; a[5] = p2[1]; a[6] = p3[0]; a[7] = p3[1];
        const char* bp = (const char*)&smem[0][0] + s * 4096 + lane * 16;
        __builtin_amdgcn_s_setprio(1);
#pragma unroll
        for (int nbb = 0; nbb < 4; ++nbb) {
            f16x8 b = *(const f16x8*)(bp + nbb * 1024);
            acc[nbb] = __builtin_amdgcn_mfma_f32_32x32x16_f16(a, b, acc[nbb], 0, 0, 0);
        }
        __builtin_amdgcn_s_setprio(0);
        if (s < 7) { xa = xa2; xb = xb2; }
    }

    // ---- Epilogue: row = (r&3) + 8*(r>>2) + 4*sub, col = nbb*32 + l31 ----
#pragma unroll
    for (int nbb = 0; nbb < 4; ++nbb)
#pragma unroll
        for (int r = 0; r < 16; ++r) {
            int crow = (r & 3) + 8 * (r >> 2) + 4 * sub;
            out[(size_t)(row0 + crow) * NOUT + nbb * 32 + l31] = acc[nbb][r];
        }
}

extern "C" void kernel_launch(void* const* d_in, const int* in_sizes, int n_in,
                              void* d_out, int out_size, void* d_ws, size_t ws_size,
                              hipStream_t stream) {
    const float* x       = (const float*)d_in[0];
    const float* coeffs  = (const float*)d_in[1];
    const float* base_w  = (const float*)d_in[2];
    _Float16* W3 = (_Float16*)d_ws;   // 72 * 4096 = 294912 bytes

    kan_prep<<<dim3(72), dim3(256), 0, stream>>>(coeffs, base_w, W3);
    kan_main<<<dim3(BATCH / 128), dim3(256), 0, stream>>>(x, W3, (float*)d_out);
}